// Round 1
// baseline (166.799 us; speedup 1.0000x reference)
//
#include <hip/hip_runtime.h>
#include <hip/hip_bf16.h>

// Problem constants (match reference)
#define BB 8
#define NN 256
#define FF 64      // F_NODE
#define EE 16      // F_EDGE
#define MM 64      // M_MSG
#define G3 192     // 3*F_NODE
#define OUTD 128
#define ROWS (BB*NN)   // 2048
#define MAXD 64        // padded neighbor capacity (Binomial(256,0.1): mean 25.6, 64 is ~8 sigma)

// ---------------------------------------------------------------------------
// k_prep: one block per (b,i) row.
//  - scan the 256 potential neighbors j, detect edges (sum of 16 feats != 0)
//  - build padded neighbor list nbr[row][slot], degree deg[row]
//  - h init = nodes
//  - Hn init = nodes @ W_n + b_msg   (W_n = W_msg rows 0..63)
// ---------------------------------------------------------------------------
__global__ __launch_bounds__(256) void k_prep(
    const float* __restrict__ nodes, const float* __restrict__ edges,
    const float* __restrict__ Wmsg, const float* __restrict__ bmsg,
    int* __restrict__ deg, int* __restrict__ nbr,
    float* __restrict__ h, float* __restrict__ hn)
{
    int row = blockIdx.x;            // b*N + i
    int tid = threadIdx.x;           // 0..255 == candidate neighbor j
    __shared__ int cnt;
    __shared__ float snode[FF];
    if (tid == 0) cnt = 0;
    __syncthreads();

    // 64B of edge features per candidate j, as 4x float4 (aligned: offset multiple of 64B)
    const float4* ep = (const float4*)(edges + (((size_t)row) * NN + tid) * EE);
    float4 a = ep[0], b4 = ep[1], c4 = ep[2], d4 = ep[3];
    float s = a.x + a.y + a.z + a.w + b4.x + b4.y + b4.z + b4.w
            + c4.x + c4.y + c4.z + c4.w + d4.x + d4.y + d4.z + d4.w;
    if (s != 0.0f) {
        int slot = atomicAdd(&cnt, 1);
        if (slot < MAXD) nbr[row * MAXD + slot] = tid;
    }
    if (tid < FF) snode[tid] = nodes[(size_t)row * FF + tid];
    __syncthreads();

    if (tid == 0) deg[row] = (cnt < MAXD) ? cnt : MAXD;
    if (tid < FF) h[row * FF + tid] = snode[tid];
    if (tid < MM) {
        float acc = bmsg[tid];
        #pragma unroll 8
        for (int k = 0; k < FF; ++k) acc += snode[k] * Wmsg[k * MM + tid];
        hn[row * MM + tid] = acc;
    }
}

// ---------------------------------------------------------------------------
// k_msg: one block (4 waves) per row. msg[row][t] = sum_slots relu(Hn[j][t] + e_ij @ W_e[:,t])
// Wave w handles slots w, w+4, ...; partial accumulators reduced via LDS.
// ---------------------------------------------------------------------------
#define MSG_WAVES 4
__global__ __launch_bounds__(256) void k_msg(
    const float* __restrict__ edges, const float* __restrict__ Wmsg,
    const int* __restrict__ deg, const int* __restrict__ nbr,
    const float* __restrict__ hn, float* __restrict__ msg)
{
    int row = blockIdx.x;
    int b   = row >> 8;              // N = 256
    int tid = threadIdx.x;
    int w   = tid >> 6;              // wave 0..3
    int t   = tid & 63;              // output feature

    // W_e column t (rows 64..79 of W_msg) -> registers; coalesced per-k, L1-resident
    float we[EE];
    #pragma unroll
    for (int k = 0; k < EE; ++k) we[k] = Wmsg[(FF + k) * MM + t];

    __shared__ float efeat[MAXD][EE];          // 4 KB
    __shared__ float part[MSG_WAVES][MM];      // 1 KB

    int d = deg[row];
    // stage this row's edge features (gather of 64B chunks) into LDS
    for (int s4 = tid; s4 < d * EE; s4 += 256) {
        int slot = s4 >> 4, k = s4 & 15;
        int j = nbr[row * MAXD + slot];
        efeat[slot][k] = edges[(((size_t)row) * NN + j) * EE + k];
    }
    __syncthreads();

    float acc = 0.0f;
    for (int s = w; s < d; s += MSG_WAVES) {
        int j = nbr[row * MAXD + s];
        float term = hn[(((size_t)b) * NN + j) * MM + t];
        #pragma unroll
        for (int k = 0; k < EE; ++k) term += efeat[s][k] * we[k];
        acc += fmaxf(term, 0.0f);
    }
    part[w][t] = acc;
    __syncthreads();
    if (w == 0) {
        msg[row * MM + t] = part[0][t] + part[1][t] + part[2][t] + part[3][t];
    }
}

// ---------------------------------------------------------------------------
// k_gru: 8 nodes per block (8 groups x 64 threads). GRU update + (unless last
// pass) Hn = h_new @ W_n + b_msg for the next pass.
// ---------------------------------------------------------------------------
#define GRU_NODES 8
__global__ __launch_bounds__(512) void k_gru(
    const float* __restrict__ Wi, const float* __restrict__ Wh,
    const float* __restrict__ bi, const float* __restrict__ bh,
    const float* __restrict__ Wmsg, const float* __restrict__ bmsg,
    const int* __restrict__ deg,
    const float* __restrict__ msg, float* __restrict__ h, float* __restrict__ hn,
    int last)
{
    int g = threadIdx.x >> 6;       // group 0..7
    int t = threadIdx.x & 63;       // feature
    int row = blockIdx.x * GRU_NODES + g;

    __shared__ float sm[GRU_NODES][FF];
    __shared__ float sh[GRU_NODES][FF];
    sm[g][t] = msg[row * MM + t];
    sh[g][t] = h[row * FF + t];
    __syncthreads();

    float ir = bi[t], iz = bi[64 + t], in_ = bi[128 + t];
    float hr = bh[t], hz = bh[64 + t], hn_ = bh[128 + t];
    #pragma unroll 4
    for (int k = 0; k < FF; ++k) {
        float mk = sm[g][k], hk = sh[g][k];   // LDS broadcast (free)
        ir  += mk * Wi[k * G3 + t];
        iz  += mk * Wi[k * G3 + 64 + t];
        in_ += mk * Wi[k * G3 + 128 + t];
        hr  += hk * Wh[k * G3 + t];
        hz  += hk * Wh[k * G3 + 64 + t];
        hn_ += hk * Wh[k * G3 + 128 + t];
    }
    float r  = 1.0f / (1.0f + __expf(-(ir + hr)));
    float z  = 1.0f / (1.0f + __expf(-(iz + hz)));
    float ng = tanhf(in_ + r * hn_);
    float hold = sh[g][t];
    float hnew = (1.0f - z) * ng + z * hold;
    if (deg[row] == 0) hnew = hold;           // node_mask scatter semantics
    h[row * FF + t] = hnew;

    __syncthreads();                          // all reads of sh done
    sh[g][t] = hnew;
    __syncthreads();

    if (!last) {
        float acc = bmsg[t];
        #pragma unroll 8
        for (int k = 0; k < FF; ++k) acc += sh[g][k] * Wmsg[k * MM + t];
        hn[row * MM + t] = acc;
    }
}

// ---------------------------------------------------------------------------
// k_readout: 8 nodes per block (8 groups x 128 threads = 1024).
// out[b][o] += sum_nodes mask * sigmoid([h,x] @ W_g + b_g)[o] * (h @ W_e + b_e)[o]
// ---------------------------------------------------------------------------
#define RO_NODES 8
__global__ __launch_bounds__(1024) void k_readout(
    const float* __restrict__ nodes, const float* __restrict__ Wg,
    const float* __restrict__ bg, const float* __restrict__ We,
    const float* __restrict__ be, const int* __restrict__ deg,
    const float* __restrict__ h, float* __restrict__ out)
{
    int g = threadIdx.x >> 7;       // group 0..7
    int o = threadIdx.x & 127;      // output channel
    int row = blockIdx.x * RO_NODES + g;     // 256 rows per b, block covers 8 rows of one b
    int b   = row >> 8;

    __shared__ float sh[RO_NODES][FF];
    __shared__ float sx[RO_NODES][FF];
    __shared__ float red[RO_NODES][OUTD];
    if (o < FF) {
        sh[g][o] = h[row * FF + o];
        sx[g][o] = nodes[(size_t)row * FF + o];
    }
    __syncthreads();

    float gacc = bg[o], eacc = be[o];
    #pragma unroll 4
    for (int k = 0; k < FF; ++k) {
        float hk = sh[g][k];
        gacc += hk * Wg[k * OUTD + o];
        eacc += hk * We[k * OUTD + o];
    }
    #pragma unroll 4
    for (int k = 0; k < FF; ++k) gacc += sx[g][k] * Wg[(FF + k) * OUTD + o];

    float val = (deg[row] != 0) ? (1.0f / (1.0f + __expf(-gacc))) * eacc : 0.0f;
    red[g][o] = val;
    __syncthreads();
    if (g == 0) {
        float s = 0.0f;
        #pragma unroll
        for (int q = 0; q < RO_NODES; ++q) s += red[q][o];
        atomicAdd(&out[b * OUTD + o], s);
    }
}

// ---------------------------------------------------------------------------
extern "C" void kernel_launch(void* const* d_in, const int* in_sizes, int n_in,
                              void* d_out, int out_size, void* d_ws, size_t ws_size,
                              hipStream_t stream) {
    const float* nodes = (const float*)d_in[0];
    const float* edges = (const float*)d_in[1];
    const float* Wmsg  = (const float*)d_in[2];
    const float* bmsg  = (const float*)d_in[3];
    const float* Wi    = (const float*)d_in[4];
    const float* Wh    = (const float*)d_in[5];
    const float* bi    = (const float*)d_in[6];
    const float* bh    = (const float*)d_in[7];
    const float* Wg    = (const float*)d_in[8];
    const float* bg    = (const float*)d_in[9];
    const float* We    = (const float*)d_in[10];
    const float* be    = (const float*)d_in[11];
    float* out = (float*)d_out;

    // workspace layout (all fully written before read; ~2.1 MB total)
    char* ws = (char*)d_ws;
    int*   deg = (int*)ws;                                    // 2048 * 4
    int*   nbr = (int*)(ws + 8192);                           // 2048*64*4 = 512 KB
    float* h   = (float*)(ws + 8192 + ROWS * MAXD * 4);       // 512 KB
    float* hn  = h + ROWS * FF;                               // 512 KB
    float* msg = hn + ROWS * MM;                              // 512 KB

    hipMemsetAsync(d_out, 0, (size_t)BB * OUTD * sizeof(float), stream);

    k_prep<<<ROWS, 256, 0, stream>>>(nodes, edges, Wmsg, bmsg, deg, nbr, h, hn);

    for (int p = 0; p < 3; ++p) {
        k_msg<<<ROWS, 256, 0, stream>>>(edges, Wmsg, deg, nbr, hn, msg);
        k_gru<<<ROWS / GRU_NODES, 64 * GRU_NODES, 0, stream>>>(
            Wi, Wh, bi, bh, Wmsg, bmsg, deg, msg, h, hn, (p == 2) ? 1 : 0);
    }

    k_readout<<<ROWS / RO_NODES, 128 * RO_NODES, 0, stream>>>(
        nodes, Wg, bg, We, be, deg, h, out);
}

// Round 2
// 156.245 us; speedup vs baseline: 1.0676x; 1.0676x over previous
//
#include <hip/hip_runtime.h>
#include <hip/hip_bf16.h>

// Problem constants (match reference)
#define BB 8
#define NN 256
#define FF 64      // F_NODE
#define EE 16      // F_EDGE
#define MM 64      // M_MSG
#define G3 192     // 3*F_NODE
#define OUTD 128
#define ROWS (BB*NN)   // 2048
#define MAXD 64        // padded neighbor capacity (Binomial(256,0.1): mean 25.6, 64 ~8 sigma)

__device__ __forceinline__ float sigmoidf_(float x) {
    return 1.0f / (1.0f + __expf(-x));
}

// ---------------------------------------------------------------------------
// k_prep: one block per (b,i) row.
//  - scan 256 candidate neighbors, deterministic compaction via ballot+scan
//  - h init = nodes; Hn init = nodes @ W_n + b_msg  (W_n = W_msg rows 0..63)
// ---------------------------------------------------------------------------
__global__ __launch_bounds__(256) void k_prep(
    const float* __restrict__ nodes, const float* __restrict__ edges,
    const float* __restrict__ Wmsg, const float* __restrict__ bmsg,
    int* __restrict__ deg, int* __restrict__ nbr,
    float* __restrict__ h, float* __restrict__ hn)
{
    int row = blockIdx.x;            // b*N + i
    int tid = threadIdx.x;           // candidate neighbor j
    int lane = tid & 63, wv = tid >> 6;
    __shared__ int wcnt[4];
    __shared__ float snode[FF];

    const float4* ep = (const float4*)(edges + (((size_t)row) * NN + tid) * EE);
    float4 a = ep[0], b4 = ep[1], c4 = ep[2], d4 = ep[3];
    float s = a.x + a.y + a.z + a.w + b4.x + b4.y + b4.z + b4.w
            + c4.x + c4.y + c4.z + c4.w + d4.x + d4.y + d4.z + d4.w;
    bool pred = (s != 0.0f);
    unsigned long long m = __ballot(pred);
    if (lane == 0) wcnt[wv] = __popcll(m);
    if (tid < FF) snode[tid] = nodes[(size_t)row * FF + tid];
    __syncthreads();

    int base = 0;
    #pragma unroll
    for (int q = 0; q < 4; ++q) base += (q < wv) ? wcnt[q] : 0;
    int slot = base + __popcll(m & ((1ull << lane) - 1ull));
    if (pred && slot < MAXD) nbr[row * MAXD + slot] = tid;

    if (tid == 0) {
        int tot = wcnt[0] + wcnt[1] + wcnt[2] + wcnt[3];
        deg[row] = (tot < MAXD) ? tot : MAXD;
    }
    if (tid < FF) h[row * FF + tid] = snode[tid];
    if (tid < MM) {
        float acc = bmsg[tid];
        #pragma unroll 8
        for (int k = 0; k < FF; ++k) acc += snode[k] * Wmsg[k * MM + tid];
        hn[row * MM + tid] = acc;
    }
}

// ---------------------------------------------------------------------------
// k_pass: one block (256 thr) per row. Fused message-aggregate + GRU update
// (+ Hn for next pass OR gated readout on the last pass).
// hn double-buffered across passes: msg phase reads hn_in (all rows),
// gru phase writes hn_out (own row) -> no cross-block race.
// ---------------------------------------------------------------------------
__global__ __launch_bounds__(256) void k_pass(
    const float* __restrict__ edges,
    const float* __restrict__ Wmsg, const float* __restrict__ bmsg,
    const float* __restrict__ Wi, const float* __restrict__ Wh,
    const float* __restrict__ bi, const float* __restrict__ bh,
    const float* __restrict__ nodes,
    const float* __restrict__ Wg, const float* __restrict__ bg,
    const float* __restrict__ We, const float* __restrict__ be,
    const int* __restrict__ deg, const int* __restrict__ nbr,
    const float* __restrict__ hn_in, float* __restrict__ hn_out,
    float* __restrict__ h, float* __restrict__ out, int last)
{
    int row = blockIdx.x, b = row >> 8;
    int tid = threadIdx.x;
    int w = tid >> 6, t = tid & 63;

    __shared__ int   snbr[MAXD];                 // neighbor indices
    __shared__ float efeat[MAXD][EE];            // 4 KB edge features
    __shared__ float part[4][MM];                // wave partials (reused)
    __shared__ float smsg[MM];
    __shared__ float shold[FF];
    __shared__ float sx[FF];
    __shared__ float gI[3][FF], gH[3][FF];
    __shared__ float shnew[FF];
    __shared__ float eo[OUTD];

    int d = deg[row];
    if (tid < d)  snbr[tid]  = nbr[row * MAXD + tid];
    if (tid < FF) shold[tid] = h[row * FF + tid];
    if (last && tid < FF) sx[tid] = nodes[(size_t)row * FF + tid];

    // W_e column t (rows 64..79 of W_msg) -> registers (L1/L2-resident)
    float we[EE];
    #pragma unroll
    for (int k = 0; k < EE; ++k) we[k] = Wmsg[(FF + k) * MM + t];
    __syncthreads();

    // stage this row's edge features into LDS (64B chunks, snbr from LDS)
    for (int s4 = tid; s4 < d * EE; s4 += 256) {
        int slot = s4 >> 4, k = s4 & 15;
        efeat[slot][k] = edges[(((size_t)row) * NN + snbr[slot]) * EE + k];
    }
    __syncthreads();

    // ---- message aggregation: msg[t] = sum_s relu(Hn[j_s][t] + e_s @ W_e[:,t])
    float acc = 0.0f;
    for (int s = w; s < d; s += 4) {
        int j = snbr[s];
        float term = hn_in[(((size_t)b) * NN + j) * MM + t];
        #pragma unroll
        for (int k = 0; k < EE; ++k) term += efeat[s][k] * we[k];
        acc += fmaxf(term, 0.0f);
    }
    part[w][t] = acc;
    __syncthreads();
    if (w == 0) smsg[t] = part[0][t] + part[1][t] + part[2][t] + part[3][t];
    __syncthreads();

    // ---- GRU gates: wave w (=gate r/z/n for w<3) computes gi, gh for feature t
    if (w < 3) {
        float gi = bi[w * FF + t], gh = bh[w * FF + t];
        #pragma unroll 4
        for (int k = 0; k < FF; ++k) {
            gi += smsg[k]  * Wi[k * G3 + w * FF + t];
            gh += shold[k] * Wh[k * G3 + w * FF + t];
        }
        gI[w][t] = gi; gH[w][t] = gh;
    }
    __syncthreads();

    if (w == 0) {
        float r  = sigmoidf_(gI[0][t] + gH[0][t]);
        float z  = sigmoidf_(gI[1][t] + gH[1][t]);
        float ng = tanhf(gI[2][t] + r * gH[2][t]);
        float hold = shold[t];
        float hnew = (1.0f - z) * ng + z * hold;
        if (d == 0) hnew = hold;               // node_mask scatter semantics
        shnew[t] = hnew;
        h[row * FF + t] = hnew;
    }
    __syncthreads();

    if (!last) {
        // Hn for next pass: hn_out = shnew @ W_n + b_msg, k split 4 ways
        float p = 0.0f;
        #pragma unroll
        for (int kk = 0; kk < 16; ++kk) {
            int k = w * 16 + kk;
            p += shnew[k] * Wmsg[k * MM + t];
        }
        part[w][t] = p;
        __syncthreads();
        if (w == 0)
            hn_out[row * MM + t] = bmsg[t] + part[0][t] + part[1][t] + part[2][t] + part[3][t];
    } else {
        // gated readout for this row; one atomicAdd per output channel
        int o = tid & 127, half = tid >> 7;
        float g = 0.0f;
        if (half == 1) {
            float e = be[o];
            #pragma unroll 4
            for (int k = 0; k < FF; ++k) e += shnew[k] * We[k * OUTD + o];
            eo[o] = e;
        } else {
            g = bg[o];
            #pragma unroll 4
            for (int k = 0; k < FF; ++k) g += shnew[k] * Wg[k * OUTD + o];
            #pragma unroll 4
            for (int k = 0; k < FF; ++k) g += sx[k] * Wg[(FF + k) * OUTD + o];
        }
        __syncthreads();
        if (half == 0 && d != 0) {
            float val = sigmoidf_(g) * eo[o];
            atomicAdd(&out[b * OUTD + o], val);
        }
    }
}

// ---------------------------------------------------------------------------
extern "C" void kernel_launch(void* const* d_in, const int* in_sizes, int n_in,
                              void* d_out, int out_size, void* d_ws, size_t ws_size,
                              hipStream_t stream) {
    const float* nodes = (const float*)d_in[0];
    const float* edges = (const float*)d_in[1];
    const float* Wmsg  = (const float*)d_in[2];
    const float* bmsg  = (const float*)d_in[3];
    const float* Wi    = (const float*)d_in[4];
    const float* Wh    = (const float*)d_in[5];
    const float* bi    = (const float*)d_in[6];
    const float* bh    = (const float*)d_in[7];
    const float* Wg    = (const float*)d_in[8];
    const float* bg    = (const float*)d_in[9];
    const float* We    = (const float*)d_in[10];
    const float* be    = (const float*)d_in[11];
    float* out = (float*)d_out;

    // workspace layout (~2.1 MB)
    char* ws = (char*)d_ws;
    int*   deg  = (int*)ws;                                   // 2048*4
    int*   nbr  = (int*)(ws + 8192);                          // 2048*64*4
    float* h    = (float*)(ws + 8192 + ROWS * MAXD * 4);
    float* hnA  = h   + ROWS * FF;
    float* hnB  = hnA + ROWS * MM;

    hipMemsetAsync(d_out, 0, (size_t)BB * OUTD * sizeof(float), stream);

    k_prep<<<ROWS, 256, 0, stream>>>(nodes, edges, Wmsg, bmsg, deg, nbr, h, hnA);

    // pass 0: hnA -> hnB ; pass 1: hnB -> hnA ; pass 2: hnA -> (readout)
    k_pass<<<ROWS, 256, 0, stream>>>(edges, Wmsg, bmsg, Wi, Wh, bi, bh,
                                     nodes, Wg, bg, We, be, deg, nbr,
                                     hnA, hnB, h, out, 0);
    k_pass<<<ROWS, 256, 0, stream>>>(edges, Wmsg, bmsg, Wi, Wh, bi, bh,
                                     nodes, Wg, bg, We, be, deg, nbr,
                                     hnB, hnA, h, out, 0);
    k_pass<<<ROWS, 256, 0, stream>>>(edges, Wmsg, bmsg, Wi, Wh, bi, bh,
                                     nodes, Wg, bg, We, be, deg, nbr,
                                     hnA, hnB, h, out, 1);
}